// Round 1
// baseline (37641.238 us; speedup 1.0000x reference)
//
#include <hip/hip_runtime.h>

#define NNODE 101
#define DIM   128
#define NHEAD 8
#define HDIMS 16
#define NSTEP 150
#define BTOT  2048
#define GE    4            // batch elements per block (512 threads, 128/elem)

#define OFF_FCT  0
#define OFF_FC1T 16512
#define OFF_MWT  (OFF_FC1T + 16384)
#define OFF_MVT  (OFF_MWT + 16384)
#define OFF_F    (OFF_MVT + 16384)
#define NORM_PROB 0.08838834764831845f

struct __align__(16) BlockState {
  float in_[GE][DIM];
  float pl[GE][DIM];
  float dec[GE][DIM];
  float q[GE][DIM];
  float qkz[GE][NHEAD][DIM];   // holds qk projections, then reused for z
  float attn[GE][DIM];
  float op[GE][DIM];
  float e[GE][NHEAD * NNODE];  // softmax buffer; first NNODE*5 floats reused as comp2 partials
  float c2[GE][NNODE];
  float mask[GE][NNODE];
  float mask1[GE][NNODE];
  float dem[GE][NNODE];
  float cap[GE];
  float lp[GE];
  int   idx[GE];
};

#define SE(g,h,n)   S.e[g][(h)*NNODE + (n)]
#define SRED(g,n,k) S.e[g][(n)*5 + (k)]

// Transpose weights + fuse F = mfc_w^T @ pk_w (once per call)
__global__ void prep_weights(const float* __restrict__ fc_w,
                             const float* __restrict__ fc1_w,
                             const float* __restrict__ mw_w,
                             const float* __restrict__ mv_w,
                             const float* __restrict__ mfc_w,
                             const float* __restrict__ pk_w,
                             float* __restrict__ ws) {
  int x = blockIdx.x * 256 + threadIdx.x;
  if (x < 16512) { int i = x >> 7, j = x & 127; ws[OFF_FCT + x] = fc_w[j * 129 + i]; return; }
  x -= 16512;
  if (x < 16384) { int i = x >> 7, j = x & 127; ws[OFF_FC1T + x] = fc1_w[j * 128 + i]; return; }
  x -= 16384;
  if (x < 16384) { int i = x >> 7, j = x & 127; ws[OFF_MWT + x] = mw_w[j * 128 + i]; return; }
  x -= 16384;
  if (x < 16384) { int i = x >> 7, j = x & 127; ws[OFF_MVT + x] = mv_w[j * 128 + i]; return; }
  x -= 16384;
  if (x < 16384) {
    int i2 = x >> 7, i = x & 127;
    float acc = 0.f;
    for (int d = 0; d < 128; ++d)
      acc = fmaf(mfc_w[d * 128 + i2], pk_w[d * 128 + i], acc);
    ws[OFF_F + x] = acc;
  }
}

__device__ __forceinline__ void mask_update(float* __restrict__ m1, float* __restrict__ m,
                                            const float* __restrict__ dem,
                                            float cap, int idx, int tl) {
  if (tl < NNODE) {
    float v1;
    if (tl == 0) v1 = (idx < 1) ? 1.f : 0.f;              // mask1[:, :nd] rule (nd=1)
    else         v1 = (tl == idx) ? 1.f : m1[tl];
    m1[tl] = v1;
    m[tl] = (dem[tl] > cap) ? 1.f : v1;
  }
  __syncthreads();
  if (tl < 64) {                                           // even waves only: uniform per wave
    bool ok = (tl == 0) || (m[tl] > 0.5f);
    if (tl + 64 < NNODE) ok = ok && (m[tl + 64] > 0.5f);
    bool alld = __all(ok);
    if (alld && tl == 0) m[0] = 0.f;                       // reopen depot when all done
  }
  __syncthreads();
}

__global__ __launch_bounds__(512, 4) void decoder_loop(
    const float* __restrict__ enc, const float* __restrict__ pool,
    const float* __restrict__ capcity, const float* __restrict__ demand,
    const float* __restrict__ mk_w,
    const float* __restrict__ ws, float* __restrict__ d_out) {
  const float* fcT  = ws + OFF_FCT;
  const float* fc1T = ws + OFF_FC1T;
  const float* mwT  = ws + OFF_MWT;
  const float* mvT  = ws + OFF_MVT;
  const float* Fm   = ws + OFF_F;

  __shared__ BlockState S;

  const int t  = threadIdx.x;
  const int g  = t >> 7;
  const int tl = t & 127;
  const int j  = tl;
  const int b  = blockIdx.x * GE + g;
  const size_t encB = (size_t)b * NNODE * DIM;
  const float NEG_INF = -__builtin_inff();
  const float cap0 = capcity[0];

  // ---- init carry ----
  S.in_[g][tl] = enc[encB + tl];                        // input0 = enc[b,0,:]
  S.pl[g][tl]  = pool[(size_t)b * DIM + tl];
  if (tl < NNODE) {
    S.dem[g][tl]   = demand[(size_t)b * NNODE + tl];
    S.mask1[g][tl] = 0.f;
  }
  if (tl == 0) { S.cap[g] = capcity[b]; S.lp[g] = 0.f; S.idx[g] = 0; }
  __syncthreads();
  mask_update(&S.mask1[g][0], &S.mask[g][0], &S.dem[g][0], S.cap[g], 0, tl);

  for (int step = 0; step < NSTEP; ++step) {
    const float cap = S.cap[g];

    // PH1: dec = [input,cap] @ fc_w^T ; pl = pl @ fc1_w^T ; dec += pl
    {
      float a_fc = 0.f, a_pl = 0.f;
      #pragma unroll 4
      for (int i = 0; i < DIM; ++i) {
        a_fc = fmaf(S.in_[g][i], fcT[i * DIM + j], a_fc);
        a_pl = fmaf(S.pl[g][i], fc1T[i * DIM + j], a_pl);
      }
      a_fc = fmaf(cap, fcT[DIM * DIM + j], a_fc);
      __syncthreads();
      S.pl[g][j]  = a_pl;
      S.dec[g][j] = a_fc + a_pl;
    }
    __syncthreads();

    // PH2: Q = dec @ mw_w^T
    {
      float acc = 0.f;
      #pragma unroll 4
      for (int i = 0; i < DIM; ++i)
        acc = fmaf(S.dec[g][i], mwT[i * DIM + j], acc);
      S.q[g][j] = acc;
    }
    __syncthreads();

    // PH2b: qk[h][i] = sum_k Q[h*16+k] * mk_w[h*16+k][i]
    {
      #pragma unroll
      for (int h = 0; h < NHEAD; ++h) {
        float acc = 0.f;
        #pragma unroll
        for (int k = 0; k < HDIMS; ++k)
          acc = fmaf(S.q[g][h * HDIMS + k], mk_w[(h * HDIMS + k) * DIM + j], acc);
        S.qkz[g][h][j] = acc;
      }
    }
    __syncthreads();

    // PH3: comp[h][n] = 0.25 * enc[n] . qk[h]   (masked -> -inf) into S.e
    {
      int h = tl & 7, nb = tl >> 3;
      const float4* qk4 = (const float4*)&S.qkz[g][h][0];
      #pragma unroll
      for (int p = 0; p < 7; ++p) {
        int n = p * 16 + nb;
        if (n < NNODE) {
          const float4* er = (const float4*)(enc + encB + (size_t)n * DIM);
          float acc = 0.f;
          #pragma unroll 8
          for (int i4 = 0; i4 < 32; ++i4) {
            float4 e4 = er[i4]; float4 q4 = qk4[i4];
            acc = fmaf(e4.x, q4.x, acc); acc = fmaf(e4.y, q4.y, acc);
            acc = fmaf(e4.z, q4.z, acc); acc = fmaf(e4.w, q4.w, acc);
          }
          SE(g, h, n) = (S.mask[g][n] > 0.5f) ? NEG_INF : 0.25f * acc;
        }
      }
    }
    __syncthreads();

    // PH4: softmax rows (one wave per (elem, 4 heads))
    {
      int w = t >> 6, lane = t & 63;
      int gg = w >> 1, hbase = (w & 1) * 4;
      #pragma unroll
      for (int hh = 0; hh < 4; ++hh) {
        int h = hbase + hh;
        float v0 = SE(gg, h, lane);
        float v1 = (lane < NNODE - 64) ? SE(gg, h, lane + 64) : NEG_INF;
        float m = fmaxf(v0, v1);
        #pragma unroll
        for (int o = 32; o > 0; o >>= 1) m = fmaxf(m, __shfl_xor(m, o, 64));
        float e0 = expf(v0 - m);
        float e1 = (lane < NNODE - 64) ? expf(v1 - m) : 0.f;
        float ss = e0 + e1;
        #pragma unroll
        for (int o = 32; o > 0; o >>= 1) ss += __shfl_xor(ss, o, 64);
        SE(gg, h, lane) = e0 / ss;
        if (lane < NNODE - 64) SE(gg, h, lane + 64) = e1 / ss;
      }
    }
    __syncthreads();

    // PH5: z[h][i] = sum_n sc[h][n] * enc[n][i]   (into qkz, qk is dead)
    {
      float acc[NHEAD];
      #pragma unroll
      for (int h = 0; h < NHEAD; ++h) acc[h] = 0.f;
      #pragma unroll 4
      for (int n = 0; n < NNODE; ++n) {
        float ev = enc[encB + (size_t)n * DIM + j];
        #pragma unroll
        for (int h = 0; h < NHEAD; ++h)
          acc[h] = fmaf(SE(g, h, n), ev, acc[h]);
      }
      #pragma unroll
      for (int h = 0; h < NHEAD; ++h) S.qkz[g][h][j] = acc[h];
    }
    __syncthreads();

    // PH5b: attn[j] = sum_i z[h(j)][i] * mv_w[j][i]
    {
      int h = j >> 4;
      float acc = 0.f;
      #pragma unroll 4
      for (int i = 0; i < DIM; ++i)
        acc = fmaf(S.qkz[g][h][i], mvT[i * DIM + j], acc);
      S.attn[g][j] = acc;
    }
    __syncthreads();

    // PH6: op[j] = sum_i2 attn[i2] * F[i2][j]   (F = mfc^T @ pk fused)
    {
      float acc = 0.f;
      #pragma unroll 4
      for (int i2 = 0; i2 < DIM; ++i2)
        acc = fmaf(S.attn[g][i2], Fm[i2 * DIM + j], acc);
      S.op[g][j] = acc;
    }
    __syncthreads();

    // PH7: comp2[n] = enc[n] . op  (4-way split partials into SRED)
    {
      int qd = tl & 3, nq = tl >> 2;
      const float4* o4 = (const float4*)&S.op[g][qd * 32];
      #pragma unroll
      for (int p = 0; p < 4; ++p) {
        int n = p * 32 + nq;
        if (n < NNODE) {
          const float4* er = (const float4*)(enc + encB + (size_t)n * DIM + qd * 32);
          float acc = 0.f;
          #pragma unroll
          for (int i4 = 0; i4 < 8; ++i4) {
            float4 e4 = er[i4]; float4 ov = o4[i4];
            acc = fmaf(e4.x, ov.x, acc); acc = fmaf(e4.y, ov.y, acc);
            acc = fmaf(e4.z, ov.z, acc); acc = fmaf(e4.w, ov.w, acc);
          }
          SRED(g, n, qd) = acc;
        }
      }
    }
    __syncthreads();
    // PH7b: logits
    if (tl < NNODE) {
      float tot = (SRED(g, tl, 0) + SRED(g, tl, 1)) + (SRED(g, tl, 2) + SRED(g, tl, 3));
      float x = tanhf(tot * NORM_PROB) * 10.f;
      S.c2[g][tl] = (S.mask[g][tl] > 0.5f) ? NEG_INF : x;
    }
    __syncthreads();

    // PH8: argmax (first-index ties) + logsumexp + scalar state update (even waves)
    if (tl < 64) {
      int lane = tl;
      float v0 = S.c2[g][lane];
      float v1 = (lane < NNODE - 64) ? S.c2[g][lane + 64] : NEG_INF;
      float bv; int bi;
      if (v1 > v0) { bv = v1; bi = lane + 64; } else { bv = v0; bi = lane; }
      #pragma unroll
      for (int o = 32; o > 0; o >>= 1) {
        float ov = __shfl_xor(bv, o, 64);
        int   oi = __shfl_xor(bi, o, 64);
        if (ov > bv || (ov == bv && oi < bi)) { bv = ov; bi = oi; }
      }
      float e0 = expf(v0 - bv);
      float e1 = (lane < NNODE - 64) ? expf(v1 - bv) : 0.f;
      float ss = e0 + e1;
      #pragma unroll
      for (int o = 32; o > 0; o >>= 1) ss += __shfl_xor(ss, o, 64);
      int c = 0;
      if (lane >= 1 && S.mask1[g][lane] > 0.5f) c++;
      if (lane + 64 < NNODE && S.mask1[g][lane + 64] > 0.5f) c++;
      #pragma unroll
      for (int o = 32; o > 0; o >>= 1) c += __shfl_xor(c, o, 64);
      if (lane == 0) {
        if (c < NNODE - 1) S.lp[g] += -logf(ss);          // is_done gating (pre-update mask1)
        d_out[(size_t)b * NSTEP + step] = (float)bi;
        S.cap[g] = (bi < 1) ? cap0 : (S.cap[g] - S.dem[g][bi]);
        S.idx[g] = bi;
      }
    }
    __syncthreads();

    // PH9: new input row + mask/mask1 update with NEW cap
    {
      int idx = S.idx[g];
      S.in_[g][j] = enc[encB + (size_t)idx * DIM + j];
      mask_update(&S.mask1[g][0], &S.mask[g][0], &S.dem[g][0], S.cap[g], idx, tl);
    }
  }

  if (tl == 0) d_out[(size_t)BTOT * NSTEP + b] = S.lp[g];
}

extern "C" void kernel_launch(void* const* d_in, const int* in_sizes, int n_in,
                              void* d_out, int out_size, void* d_ws, size_t ws_size,
                              hipStream_t stream) {
  const float* enc   = (const float*)d_in[0];
  const float* pool  = (const float*)d_in[1];
  const float* cap   = (const float*)d_in[2];
  const float* dem   = (const float*)d_in[3];
  const float* fc_w  = (const float*)d_in[7];
  const float* fc1_w = (const float*)d_in[8];
  const float* pk_w  = (const float*)d_in[9];
  const float* mw_w  = (const float*)d_in[10];
  const float* mk_w  = (const float*)d_in[11];
  const float* mv_w  = (const float*)d_in[12];
  const float* mfc_w = (const float*)d_in[13];
  float* out = (float*)d_out;
  float* ws  = (float*)d_ws;

  prep_weights<<<321, 256, 0, stream>>>(fc_w, fc1_w, mw_w, mv_w, mfc_w, pk_w, ws);
  decoder_loop<<<BTOT / GE, 512, 0, stream>>>(enc, pool, cap, dem, mk_w, ws, out);
}

// Round 3
// 34454.803 us; speedup vs baseline: 1.0925x; 1.0925x over previous
//
#include <hip/hip_runtime.h>

#define NNODE 101
#define DIM   128
#define NHEAD 8
#define NSTEP 150
#define BTOT  2048
#define GE    4            // batch elements per block (512 threads, 128/elem)

#define OFF_FCT  0
#define OFF_FC1T 16512
#define OFF_MWT  (OFF_FC1T + 16384)
#define OFF_MVT  (OFF_MWT + 16384)
#define OFF_F    (OFF_MVT + 16384)
#define NORM_PROB 0.08838834764831845f

// LDS layout. U region per g (2112 floats) is time-multiplexed:
//   qk  (PH2b..PH3): h*132 + i    (stride 132 => distinct bank-quad per head -> conflict-free)
//   z   (PH5..PH5b): h*132 + i    (same property)
//   comp(PH3..PH4):  1056 + h*104 + n
// sc region per g (1212 floats): sc[n*12+h] (PH4..PH5, broadcast float4 reads),
//   then SRED[n*12+k] (PH7..PH7b)
struct __align__(16) BS {
  float in_[GE][DIM];
  float pl[GE][DIM];
  float dec[GE][DIM];
  float q[GE][DIM];
  float attn[GE][DIM];
  float op[GE][DIM];
  float U[GE][2112];
  float sc[GE][1212];
  float c2[GE][NNODE];
  float mask[GE][NNODE];
  float mask1[GE][NNODE];
  float dem[GE][NNODE];
  float cap[GE];
  float lp[GE];
  int   idx[GE];
};

#define QK(g,h,i)    S.U[g][(h)*132 + (i)]
#define ZR(g,h,i)    S.U[g][(h)*132 + (i)]
#define CMP(g,h,n)   S.U[g][1056 + (h)*104 + (n)]
#define SC(g,n,h)    S.sc[g][(n)*12 + (h)]
#define SRED(g,n,k)  S.sc[g][(n)*12 + (k)]

// Transpose weights + fuse F = mfc_w^T @ pk_w (once per call)
__global__ void prep_weights(const float* __restrict__ fc_w,
                             const float* __restrict__ fc1_w,
                             const float* __restrict__ mw_w,
                             const float* __restrict__ mv_w,
                             const float* __restrict__ mfc_w,
                             const float* __restrict__ pk_w,
                             float* __restrict__ ws) {
  int x = blockIdx.x * 256 + threadIdx.x;
  if (x < 16512) { int i = x >> 7, j = x & 127; ws[OFF_FCT + x] = fc_w[j * 129 + i]; return; }
  x -= 16512;
  if (x < 16384) { int i = x >> 7, j = x & 127; ws[OFF_FC1T + x] = fc1_w[j * 128 + i]; return; }
  x -= 16384;
  if (x < 16384) { int i = x >> 7, j = x & 127; ws[OFF_MWT + x] = mw_w[j * 128 + i]; return; }
  x -= 16384;
  if (x < 16384) { int i = x >> 7, j = x & 127; ws[OFF_MVT + x] = mv_w[j * 128 + i]; return; }
  x -= 16384;
  if (x < 16384) {
    int i2 = x >> 7, i = x & 127;
    float acc = 0.f;
    for (int d = 0; d < 128; ++d)
      acc = fmaf(mfc_w[d * 128 + i2], pk_w[d * 128 + i], acc);
    ws[OFF_F + x] = acc;
  }
}

__device__ __forceinline__ void mask_update(float* __restrict__ m1, float* __restrict__ m,
                                            const float* __restrict__ dem,
                                            float cap, int idx, int tl) {
  if (tl < NNODE) {
    float v1;
    if (tl == 0) v1 = (idx < 1) ? 1.f : 0.f;              // mask1[:, :nd] rule (nd=1)
    else         v1 = (tl == idx) ? 1.f : m1[tl];
    m1[tl] = v1;
    m[tl] = (dem[tl] > cap) ? 1.f : v1;
  }
  __syncthreads();
  if (tl < 64) {
    bool ok = (tl == 0) || (m[tl] > 0.5f);
    if (tl + 64 < NNODE) ok = ok && (m[tl + 64] > 0.5f);
    bool alld = __all(ok);
    if (alld && tl == 0) m[0] = 0.f;                       // reopen depot when all done
  }
  __syncthreads();
}

__global__ __launch_bounds__(512, 4) void decoder_loop(
    const float* __restrict__ enc, const float* __restrict__ pool,
    const float* __restrict__ capcity, const float* __restrict__ demand,
    const float* __restrict__ mk_w,
    const float* __restrict__ ws, float* __restrict__ d_out) {
  const float* fcT  = ws + OFF_FCT;
  const float* fc1T = ws + OFF_FC1T;
  const float* mwT  = ws + OFF_MWT;
  const float* mvT  = ws + OFF_MVT;
  const float* Fm   = ws + OFF_F;

  __shared__ BS S;

  const int t  = threadIdx.x;
  const int g  = t >> 7;
  const int tl = t & 127;
  const int j  = tl;
  const int b  = blockIdx.x * GE + g;
  const size_t encB = (size_t)b * NNODE * DIM;
  const float NEG_INF = -__builtin_inff();
  const float cap0 = capcity[0];

  // ---- init carry ----
  S.in_[g][tl] = enc[encB + tl];                        // input0 = enc[b,0,:]
  S.pl[g][tl]  = pool[(size_t)b * DIM + tl];
  if (tl < NNODE) {
    S.dem[g][tl]   = demand[(size_t)b * NNODE + tl];
    S.mask1[g][tl] = 0.f;
  }
  if (tl == 0) { S.cap[g] = capcity[b]; S.lp[g] = 0.f; S.idx[g] = 0; }
  __syncthreads();
  mask_update(&S.mask1[g][0], &S.mask[g][0], &S.dem[g][0], S.cap[g], 0, tl);

  for (int step = 0; step < NSTEP; ++step) {
    const float cap = S.cap[g];

    // PH1: dec = [input,cap] @ fc_w^T ; pl = pl @ fc1_w^T ; dec += pl
    // (single sequential accumulators, i ascending — bit-identical to R1)
    {
      const float4* x4 = (const float4*)&S.in_[g][0];
      const float4* p4 = (const float4*)&S.pl[g][0];
      float a_fc = 0.f, a_pl = 0.f;
      #pragma unroll 4
      for (int i4 = 0; i4 < 32; ++i4) {
        float4 xv = x4[i4], pv = p4[i4];
        const float* wf = fcT  + (i4 * 4) * DIM + j;
        const float* wp = fc1T + (i4 * 4) * DIM + j;
        a_fc = fmaf(xv.x, wf[0],       a_fc);
        a_fc = fmaf(xv.y, wf[DIM],     a_fc);
        a_fc = fmaf(xv.z, wf[2 * DIM], a_fc);
        a_fc = fmaf(xv.w, wf[3 * DIM], a_fc);
        a_pl = fmaf(pv.x, wp[0],       a_pl);
        a_pl = fmaf(pv.y, wp[DIM],     a_pl);
        a_pl = fmaf(pv.z, wp[2 * DIM], a_pl);
        a_pl = fmaf(pv.w, wp[3 * DIM], a_pl);
      }
      a_fc = fmaf(cap, fcT[DIM * DIM + j], a_fc);
      __syncthreads();
      S.pl[g][j]  = a_pl;
      S.dec[g][j] = a_fc + a_pl;
    }
    __syncthreads();

    // PH2: Q = dec @ mw_w^T  (sequential chain, i ascending)
    {
      const float4* x4 = (const float4*)&S.dec[g][0];
      float acc = 0.f;
      #pragma unroll 4
      for (int i4 = 0; i4 < 32; ++i4) {
        float4 xv = x4[i4];
        const float* w = mwT + (i4 * 4) * DIM + j;
        acc = fmaf(xv.x, w[0],       acc);
        acc = fmaf(xv.y, w[DIM],     acc);
        acc = fmaf(xv.z, w[2 * DIM], acc);
        acc = fmaf(xv.w, w[3 * DIM], acc);
      }
      S.q[g][j] = acc;
    }
    __syncthreads();

    // PH2b: qk[h][j] = sum_k Q[h*16+k] * mk_w[h*16+k][j]  (k ascending; write stride 132)
    {
      const float4* q4 = (const float4*)&S.q[g][0];
      #pragma unroll
      for (int h = 0; h < NHEAD; ++h) {
        float4 qa = q4[h * 4 + 0], qb = q4[h * 4 + 1], qc = q4[h * 4 + 2], qd4 = q4[h * 4 + 3];
        const float* w = mk_w + (h * 16) * DIM + j;
        float acc = 0.f;
        acc = fmaf(qa.x, w[0],        acc); acc = fmaf(qa.y, w[DIM],      acc);
        acc = fmaf(qa.z, w[2 * DIM],  acc); acc = fmaf(qa.w, w[3 * DIM],  acc);
        acc = fmaf(qb.x, w[4 * DIM],  acc); acc = fmaf(qb.y, w[5 * DIM],  acc);
        acc = fmaf(qb.z, w[6 * DIM],  acc); acc = fmaf(qb.w, w[7 * DIM],  acc);
        acc = fmaf(qc.x, w[8 * DIM],  acc); acc = fmaf(qc.y, w[9 * DIM],  acc);
        acc = fmaf(qc.z, w[10 * DIM], acc); acc = fmaf(qc.w, w[11 * DIM], acc);
        acc = fmaf(qd4.x, w[12 * DIM], acc); acc = fmaf(qd4.y, w[13 * DIM], acc);
        acc = fmaf(qd4.z, w[14 * DIM], acc); acc = fmaf(qd4.w, w[15 * DIM], acc);
        QK(g, h, j) = acc;
      }
    }
    __syncthreads();

    // PH3: comp[h][n] = 0.25 * enc[n].qk[h] — qk float4 read once per i4 (conflict-free),
    // per-acc order: i ascending, x->y->z->w sequential (bit-identical to R1)
    {
      int h = tl & 7, nb = tl >> 3;       // nb in 0..15
      float acc[7] = {0.f, 0.f, 0.f, 0.f, 0.f, 0.f, 0.f};
      for (int i4 = 0; i4 < 32; ++i4) {
        float4 qv = *(const float4*)&QK(g, h, i4 * 4);
        #pragma unroll
        for (int p = 0; p < 7; ++p) {
          int n = p * 16 + nb;
          if (n < NNODE) {
            float4 e4 = *(const float4*)(enc + encB + (size_t)n * DIM + i4 * 4);
            acc[p] = fmaf(e4.x, qv.x, acc[p]);
            acc[p] = fmaf(e4.y, qv.y, acc[p]);
            acc[p] = fmaf(e4.z, qv.z, acc[p]);
            acc[p] = fmaf(e4.w, qv.w, acc[p]);
          }
        }
      }
      #pragma unroll
      for (int p = 0; p < 7; ++p) {
        int n = p * 16 + nb;
        if (n < NNODE)
          CMP(g, h, n) = (S.mask[g][n] > 0.5f) ? NEG_INF : 0.25f * acc[p];
      }
    }
    __syncthreads();

    // PH4: softmax rows; write TRANSPOSED sc[n][h] (stride 12)
    {
      int w = t >> 6, lane = t & 63;
      int gg = w >> 1, hb = (w & 1) * 4;
      #pragma unroll
      for (int hh = 0; hh < 4; ++hh) {
        int h = hb + hh;
        float v0 = CMP(gg, h, lane);
        float v1 = (lane < NNODE - 64) ? CMP(gg, h, lane + 64) : NEG_INF;
        float m = fmaxf(v0, v1);
        #pragma unroll
        for (int o = 32; o > 0; o >>= 1) m = fmaxf(m, __shfl_xor(m, o, 64));
        float e0 = expf(v0 - m);
        float e1 = (lane < NNODE - 64) ? expf(v1 - m) : 0.f;
        float ss = e0 + e1;
        #pragma unroll
        for (int o = 32; o > 0; o >>= 1) ss += __shfl_xor(ss, o, 64);
        SC(gg, lane, h) = e0 / ss;
        if (lane < NNODE - 64) SC(gg, lane + 64, h) = e1 / ss;
      }
    }
    __syncthreads();

    // PH5: z[h][j] = sum_n sc[n][h]*enc[n][j] — thread j owns dim j, n ascending 0..100
    // (bit-identical order to R1; sc reads are broadcast float4 -> conflict-free)
    {
      float acc[NHEAD] = {0.f,0.f,0.f,0.f,0.f,0.f,0.f,0.f};
      #pragma unroll 4
      for (int n = 0; n < NNODE; ++n) {
        float4 s0 = *(const float4*)&SC(g, n, 0);
        float4 s1 = *(const float4*)&SC(g, n, 4);
        float ev = enc[encB + (size_t)n * DIM + j];
        acc[0] = fmaf(s0.x, ev, acc[0]);
        acc[1] = fmaf(s0.y, ev, acc[1]);
        acc[2] = fmaf(s0.z, ev, acc[2]);
        acc[3] = fmaf(s0.w, ev, acc[3]);
        acc[4] = fmaf(s1.x, ev, acc[4]);
        acc[5] = fmaf(s1.y, ev, acc[5]);
        acc[6] = fmaf(s1.z, ev, acc[6]);
        acc[7] = fmaf(s1.w, ev, acc[7]);
      }
      __syncthreads();                       // QK region dead; reuse as ZR
      #pragma unroll
      for (int h = 0; h < NHEAD; ++h) ZR(g, h, j) = acc[h];
    }
    __syncthreads();

    // PH5b: attn[j] = sum_i z[h(j)][i] * mv_w[j][i]  (i ascending, x->y->z->w)
    {
      int h = j >> 4;
      float acc = 0.f;
      #pragma unroll 4
      for (int i4 = 0; i4 < 32; ++i4) {
        float4 zv = *(const float4*)&ZR(g, h, i4 * 4);
        const float* w = mvT + (i4 * 4) * DIM + j;
        acc = fmaf(zv.x, w[0],       acc);
        acc = fmaf(zv.y, w[DIM],     acc);
        acc = fmaf(zv.z, w[2 * DIM], acc);
        acc = fmaf(zv.w, w[3 * DIM], acc);
      }
      S.attn[g][j] = acc;
    }
    __syncthreads();

    // PH6: op[j] = sum_i attn[i] * F[i][j]  (sequential, i ascending)
    {
      const float4* x4 = (const float4*)&S.attn[g][0];
      float acc = 0.f;
      #pragma unroll 4
      for (int i4 = 0; i4 < 32; ++i4) {
        float4 xv = x4[i4];
        const float* w = Fm + (i4 * 4) * DIM + j;
        acc = fmaf(xv.x, w[0],       acc);
        acc = fmaf(xv.y, w[DIM],     acc);
        acc = fmaf(xv.z, w[2 * DIM], acc);
        acc = fmaf(xv.w, w[3 * DIM], acc);
      }
      S.op[g][j] = acc;
    }
    __syncthreads();

    // PH7: comp2[n] = enc[n].op — 4-way dim split, i4 ascending (no rotation; R1 order)
    {
      int qd = tl & 3, nq = tl >> 2;       // nq 0..31
      #pragma unroll
      for (int p = 0; p < 4; ++p) {
        int n = p * 32 + nq;
        if (n < NNODE) {
          float acc = 0.f;
          #pragma unroll
          for (int i4 = 0; i4 < 8; ++i4) {
            float4 ov = *(const float4*)&S.op[g][qd * 32 + i4 * 4];
            float4 e4 = *(const float4*)(enc + encB + (size_t)n * DIM + qd * 32 + i4 * 4);
            acc = fmaf(e4.x, ov.x, acc);
            acc = fmaf(e4.y, ov.y, acc);
            acc = fmaf(e4.z, ov.z, acc);
            acc = fmaf(e4.w, ov.w, acc);
          }
          SRED(g, n, qd) = acc;
        }
      }
    }
    __syncthreads();
    // PH7b: logits  — tot = (q0+q1)+(q2+q3), same pairing as R1
    if (tl < NNODE) {
      float4 r = *(const float4*)&SRED(g, tl, 0);
      float tot = (r.x + r.y) + (r.z + r.w);
      float x = tanhf(tot * NORM_PROB) * 10.f;
      S.c2[g][tl] = (S.mask[g][tl] > 0.5f) ? NEG_INF : x;
    }
    __syncthreads();

    // PH8: argmax (first-index ties) + logsumexp + scalar state update (wave A of group)
    if (tl < 64) {
      int lane = tl;
      float v0 = S.c2[g][lane];
      float v1 = (lane < NNODE - 64) ? S.c2[g][lane + 64] : NEG_INF;
      float bv; int bi;
      if (v1 > v0) { bv = v1; bi = lane + 64; } else { bv = v0; bi = lane; }
      #pragma unroll
      for (int o = 32; o > 0; o >>= 1) {
        float ov = __shfl_xor(bv, o, 64);
        int   oi = __shfl_xor(bi, o, 64);
        if (ov > bv || (ov == bv && oi < bi)) { bv = ov; bi = oi; }
      }
      float e0 = expf(v0 - bv);
      float e1 = (lane < NNODE - 64) ? expf(v1 - bv) : 0.f;
      float ss = e0 + e1;
      #pragma unroll
      for (int o = 32; o > 0; o >>= 1) ss += __shfl_xor(ss, o, 64);
      int c = 0;
      if (lane >= 1 && S.mask1[g][lane] > 0.5f) c++;
      if (lane + 64 < NNODE && S.mask1[g][lane + 64] > 0.5f) c++;
      #pragma unroll
      for (int o = 32; o > 0; o >>= 1) c += __shfl_xor(c, o, 64);
      if (lane == 0) {
        if (c < NNODE - 1) S.lp[g] += -logf(ss);          // is_done gating (pre-update mask1)
        d_out[(size_t)b * NSTEP + step] = (float)bi;
        S.cap[g] = (bi < 1) ? cap0 : (S.cap[g] - S.dem[g][bi]);
        S.idx[g] = bi;
      }
    }
    __syncthreads();

    // PH9: new input row + mask/mask1 update with NEW cap
    {
      int idx = S.idx[g];
      S.in_[g][j] = enc[encB + (size_t)idx * DIM + j];
      mask_update(&S.mask1[g][0], &S.mask[g][0], &S.dem[g][0], S.cap[g], idx, tl);
    }
  }

  if (tl == 0) d_out[(size_t)BTOT * NSTEP + b] = S.lp[g];
}

extern "C" void kernel_launch(void* const* d_in, const int* in_sizes, int n_in,
                              void* d_out, int out_size, void* d_ws, size_t ws_size,
                              hipStream_t stream) {
  const float* enc   = (const float*)d_in[0];
  const float* pool  = (const float*)d_in[1];
  const float* cap   = (const float*)d_in[2];
  const float* dem   = (const float*)d_in[3];
  const float* fc_w  = (const float*)d_in[7];
  const float* fc1_w = (const float*)d_in[8];
  const float* pk_w  = (const float*)d_in[9];
  const float* mw_w  = (const float*)d_in[10];
  const float* mk_w  = (const float*)d_in[11];
  const float* mv_w  = (const float*)d_in[12];
  const float* mfc_w = (const float*)d_in[13];
  float* out = (float*)d_out;
  float* ws  = (float*)d_ws;

  prep_weights<<<321, 256, 0, stream>>>(fc_w, fc1_w, mw_w, mv_w, mfc_w, pk_w, ws);
  decoder_loop<<<BTOT / GE, 512, 0, stream>>>(enc, pool, cap, dem, mk_w, ws, out);
}

// Round 4
// 17726.083 us; speedup vs baseline: 2.1235x; 1.9437x over previous
//
#include <hip/hip_runtime.h>

#define NNODE 101
#define DIM   128
#define NHEAD 8
#define NSTEP 150
#define BTOT  2048
#define ENCP  132          // padded enc row stride in LDS (bank-quad spread)

#define OFF_FCT  0
#define OFF_FC1T 16512
#define OFF_MWT  (OFF_FC1T + 16384)
#define OFF_MVT  (OFF_MWT + 16384)
#define OFF_F    (OFF_MVT + 16384)
#define NORM_PROB 0.08838834764831845f

// One block = one batch element, 128 threads (2 waves), enc slice resident in LDS.
// U region (2112 floats) time-multiplexed:
//   qk (PH2b..PH3): h*132 + i   z (PH5..PH5b): h*132 + i   comp (PH3..PH4): 1056 + h*104 + n
// sc region (1212): sc[n*12+h] (PH4..PH5) then SRED[n*12+k] (PH7..PH7b)
struct __align__(16) BS {
  float enc[NNODE * ENCP];   // 53328 B
  float in_[DIM];
  float pl[DIM];
  float dec[DIM];
  float q[DIM];
  float attn[DIM];
  float op[DIM];
  float U[2112];
  float sc[1212];
  float c2[NNODE];
  float mask[NNODE];
  float mask1[NNODE];
  float dem[NNODE];
  float cap;
  float lp;
  int   idx;
};

#define EL(n,i)     S.enc[(n)*ENCP + (i)]
#define QK(h,i)     S.U[(h)*132 + (i)]
#define ZR(h,i)     S.U[(h)*132 + (i)]
#define CMP(h,n)    S.U[1056 + (h)*104 + (n)]
#define SC(n,h)     S.sc[(n)*12 + (h)]
#define SRED(n,k)   S.sc[(n)*12 + (k)]

// Transpose weights + fuse F = mfc_w^T @ pk_w (once per call)
__global__ void prep_weights(const float* __restrict__ fc_w,
                             const float* __restrict__ fc1_w,
                             const float* __restrict__ mw_w,
                             const float* __restrict__ mv_w,
                             const float* __restrict__ mfc_w,
                             const float* __restrict__ pk_w,
                             float* __restrict__ ws) {
  int x = blockIdx.x * 256 + threadIdx.x;
  if (x < 16512) { int i = x >> 7, j = x & 127; ws[OFF_FCT + x] = fc_w[j * 129 + i]; return; }
  x -= 16512;
  if (x < 16384) { int i = x >> 7, j = x & 127; ws[OFF_FC1T + x] = fc1_w[j * 128 + i]; return; }
  x -= 16384;
  if (x < 16384) { int i = x >> 7, j = x & 127; ws[OFF_MWT + x] = mw_w[j * 128 + i]; return; }
  x -= 16384;
  if (x < 16384) { int i = x >> 7, j = x & 127; ws[OFF_MVT + x] = mv_w[j * 128 + i]; return; }
  x -= 16384;
  if (x < 16384) {
    int i2 = x >> 7, i = x & 127;
    float acc = 0.f;
    for (int d = 0; d < 128; ++d)
      acc = fmaf(mfc_w[d * 128 + i2], pk_w[d * 128 + i], acc);
    ws[OFF_F + x] = acc;
  }
}

__global__ __launch_bounds__(128, 1) void decoder_loop(
    const float* __restrict__ enc, const float* __restrict__ pool,
    const float* __restrict__ capcity, const float* __restrict__ demand,
    const float* __restrict__ mk_w,
    const float* __restrict__ ws, float* __restrict__ d_out) {
  const float* fcT  = ws + OFF_FCT;
  const float* fc1T = ws + OFF_FC1T;
  const float* mwT  = ws + OFF_MWT;
  const float* mvT  = ws + OFF_MVT;
  const float* Fm   = ws + OFF_F;

  __shared__ BS S;

  const int tl = threadIdx.x;          // 0..127
  const int j  = tl;
  const int b  = blockIdx.x;
  const size_t encB = (size_t)b * NNODE * DIM;
  const float NEG_INF = -__builtin_inff();
  const float cap0 = capcity[0];

  // ---- stage enc slice into LDS (padded rows), coalesced float4 ----
  for (int x = tl; x < NNODE * 32; x += 128) {
    int n = x >> 5, c = x & 31;
    float4 v = *(const float4*)(enc + encB + (size_t)n * DIM + c * 4);
    *(float4*)&EL(n, c * 4) = v;
  }
  __syncthreads();

  // ---- init carry ----
  S.in_[tl] = EL(0, tl);                               // input0 = enc[b,0,:]
  S.pl[tl]  = pool[(size_t)b * DIM + tl];
  if (tl < NNODE) {
    S.dem[tl]   = demand[(size_t)b * NNODE + tl];
    S.mask1[tl] = 0.f;
  }
  if (tl == 0) { S.cap = capcity[b]; S.lp = 0.f; S.idx = 0; }
  __syncthreads();
  // mask_update(cap, idx=0)
  {
    if (tl < NNODE) {
      float v1 = (tl == 0) ? 1.f : 0.f;
      S.mask1[tl] = v1;
      S.mask[tl] = (S.dem[tl] > S.cap) ? 1.f : v1;
    }
    __syncthreads();
    if (tl < 64) {
      bool ok = (tl == 0) || (S.mask[tl] > 0.5f);
      if (tl + 64 < NNODE) ok = ok && (S.mask[tl + 64] > 0.5f);
      bool alld = __all(ok);
      if (alld && tl == 0) S.mask[0] = 0.f;
    }
    __syncthreads();
  }

  for (int step = 0; step < NSTEP; ++step) {
    const float cap = S.cap;

    // PH1: dec = [input,cap] @ fc_w^T ; pl = pl @ fc1_w^T ; dec += pl
    {
      const float4* x4 = (const float4*)&S.in_[0];
      const float4* p4 = (const float4*)&S.pl[0];
      float a_fc = 0.f, a_pl = 0.f;
      #pragma unroll 4
      for (int i4 = 0; i4 < 32; ++i4) {
        float4 xv = x4[i4], pv = p4[i4];
        const float* wf = fcT  + (i4 * 4) * DIM + j;
        const float* wp = fc1T + (i4 * 4) * DIM + j;
        a_fc = fmaf(xv.x, wf[0],       a_fc);
        a_fc = fmaf(xv.y, wf[DIM],     a_fc);
        a_fc = fmaf(xv.z, wf[2 * DIM], a_fc);
        a_fc = fmaf(xv.w, wf[3 * DIM], a_fc);
        a_pl = fmaf(pv.x, wp[0],       a_pl);
        a_pl = fmaf(pv.y, wp[DIM],     a_pl);
        a_pl = fmaf(pv.z, wp[2 * DIM], a_pl);
        a_pl = fmaf(pv.w, wp[3 * DIM], a_pl);
      }
      a_fc = fmaf(cap, fcT[DIM * DIM + j], a_fc);
      __syncthreads();
      S.pl[j]  = a_pl;
      S.dec[j] = a_fc + a_pl;
    }
    __syncthreads();

    // PH2: Q = dec @ mw_w^T
    {
      const float4* x4 = (const float4*)&S.dec[0];
      float acc = 0.f;
      #pragma unroll 4
      for (int i4 = 0; i4 < 32; ++i4) {
        float4 xv = x4[i4];
        const float* w = mwT + (i4 * 4) * DIM + j;
        acc = fmaf(xv.x, w[0],       acc);
        acc = fmaf(xv.y, w[DIM],     acc);
        acc = fmaf(xv.z, w[2 * DIM], acc);
        acc = fmaf(xv.w, w[3 * DIM], acc);
      }
      S.q[j] = acc;
    }
    __syncthreads();

    // PH2b: qk[h][j] = sum_k Q[h*16+k] * mk_w[h*16+k][j]
    {
      const float4* q4 = (const float4*)&S.q[0];
      #pragma unroll
      for (int h = 0; h < NHEAD; ++h) {
        float4 qa = q4[h * 4 + 0], qb = q4[h * 4 + 1], qc = q4[h * 4 + 2], qd4 = q4[h * 4 + 3];
        const float* w = mk_w + (h * 16) * DIM + j;
        float acc = 0.f;
        acc = fmaf(qa.x, w[0],        acc); acc = fmaf(qa.y, w[DIM],      acc);
        acc = fmaf(qa.z, w[2 * DIM],  acc); acc = fmaf(qa.w, w[3 * DIM],  acc);
        acc = fmaf(qb.x, w[4 * DIM],  acc); acc = fmaf(qb.y, w[5 * DIM],  acc);
        acc = fmaf(qb.z, w[6 * DIM],  acc); acc = fmaf(qb.w, w[7 * DIM],  acc);
        acc = fmaf(qc.x, w[8 * DIM],  acc); acc = fmaf(qc.y, w[9 * DIM],  acc);
        acc = fmaf(qc.z, w[10 * DIM], acc); acc = fmaf(qc.w, w[11 * DIM], acc);
        acc = fmaf(qd4.x, w[12 * DIM], acc); acc = fmaf(qd4.y, w[13 * DIM], acc);
        acc = fmaf(qd4.z, w[14 * DIM], acc); acc = fmaf(qd4.w, w[15 * DIM], acc);
        QK(h, j) = acc;
      }
    }
    __syncthreads();

    // PH3: comp[h][n] = 0.25 * enc[n].qk[h]  (enc from LDS; order identical to R3)
    {
      int h = tl & 7, nb = tl >> 3;       // nb in 0..15
      float acc[7] = {0.f, 0.f, 0.f, 0.f, 0.f, 0.f, 0.f};
      for (int i4 = 0; i4 < 32; ++i4) {
        float4 qv = *(const float4*)&QK(h, i4 * 4);
        #pragma unroll
        for (int p = 0; p < 7; ++p) {
          int n = p * 16 + nb;
          if (n < NNODE) {
            float4 e4 = *(const float4*)&EL(n, i4 * 4);
            acc[p] = fmaf(e4.x, qv.x, acc[p]);
            acc[p] = fmaf(e4.y, qv.y, acc[p]);
            acc[p] = fmaf(e4.z, qv.z, acc[p]);
            acc[p] = fmaf(e4.w, qv.w, acc[p]);
          }
        }
      }
      #pragma unroll
      for (int p = 0; p < 7; ++p) {
        int n = p * 16 + nb;
        if (n < NNODE)
          CMP(h, n) = (S.mask[n] > 0.5f) ? NEG_INF : 0.25f * acc[p];
      }
    }
    __syncthreads();

    // PH4: softmax rows; write transposed sc[n][h]
    {
      int w = tl >> 6, lane = tl & 63;
      int hb = w * 4;
      #pragma unroll
      for (int hh = 0; hh < 4; ++hh) {
        int h = hb + hh;
        float v0 = CMP(h, lane);
        float v1 = (lane < NNODE - 64) ? CMP(h, lane + 64) : NEG_INF;
        float m = fmaxf(v0, v1);
        #pragma unroll
        for (int o = 32; o > 0; o >>= 1) m = fmaxf(m, __shfl_xor(m, o, 64));
        float e0 = expf(v0 - m);
        float e1 = (lane < NNODE - 64) ? expf(v1 - m) : 0.f;
        float ss = e0 + e1;
        #pragma unroll
        for (int o = 32; o > 0; o >>= 1) ss += __shfl_xor(ss, o, 64);
        SC(lane, h) = e0 / ss;
        if (lane < NNODE - 64) SC(lane + 64, h) = e1 / ss;
      }
    }
    __syncthreads();

    // PH5: z[h][j] = sum_n sc[n][h]*enc[n][j]  (n ascending; enc from LDS)
    {
      float acc[NHEAD] = {0.f,0.f,0.f,0.f,0.f,0.f,0.f,0.f};
      #pragma unroll 4
      for (int n = 0; n < NNODE; ++n) {
        float4 s0 = *(const float4*)&SC(n, 0);
        float4 s1 = *(const float4*)&SC(n, 4);
        float ev = EL(n, j);
        acc[0] = fmaf(s0.x, ev, acc[0]);
        acc[1] = fmaf(s0.y, ev, acc[1]);
        acc[2] = fmaf(s0.z, ev, acc[2]);
        acc[3] = fmaf(s0.w, ev, acc[3]);
        acc[4] = fmaf(s1.x, ev, acc[4]);
        acc[5] = fmaf(s1.y, ev, acc[5]);
        acc[6] = fmaf(s1.z, ev, acc[6]);
        acc[7] = fmaf(s1.w, ev, acc[7]);
      }
      // ZR (=QK region) last read in PH3, guarded by the PH3/PH4 barriers -> safe to write now
      #pragma unroll
      for (int h = 0; h < NHEAD; ++h) ZR(h, j) = acc[h];
    }
    __syncthreads();

    // PH5b: attn[j] = sum_i z[h(j)][i] * mv_w[j][i]
    {
      int h = j >> 4;
      float acc = 0.f;
      #pragma unroll 4
      for (int i4 = 0; i4 < 32; ++i4) {
        float4 zv = *(const float4*)&ZR(h, i4 * 4);
        const float* w = mvT + (i4 * 4) * DIM + j;
        acc = fmaf(zv.x, w[0],       acc);
        acc = fmaf(zv.y, w[DIM],     acc);
        acc = fmaf(zv.z, w[2 * DIM], acc);
        acc = fmaf(zv.w, w[3 * DIM], acc);
      }
      S.attn[j] = acc;
    }
    __syncthreads();

    // PH6: op[j] = sum_i attn[i] * F[i][j]
    {
      const float4* x4 = (const float4*)&S.attn[0];
      float acc = 0.f;
      #pragma unroll 4
      for (int i4 = 0; i4 < 32; ++i4) {
        float4 xv = x4[i4];
        const float* w = Fm + (i4 * 4) * DIM + j;
        acc = fmaf(xv.x, w[0],       acc);
        acc = fmaf(xv.y, w[DIM],     acc);
        acc = fmaf(xv.z, w[2 * DIM], acc);
        acc = fmaf(xv.w, w[3 * DIM], acc);
      }
      S.op[j] = acc;
    }
    __syncthreads();

    // PH7: comp2[n] = enc[n].op — 4-way dim split (enc from LDS; order identical)
    {
      int qd = tl & 3, nq = tl >> 2;       // nq 0..31
      #pragma unroll
      for (int p = 0; p < 4; ++p) {
        int n = p * 32 + nq;
        if (n < NNODE) {
          float acc = 0.f;
          #pragma unroll
          for (int i4 = 0; i4 < 8; ++i4) {
            float4 ov = *(const float4*)&S.op[qd * 32 + i4 * 4];
            float4 e4 = *(const float4*)&EL(n, qd * 32 + i4 * 4);
            acc = fmaf(e4.x, ov.x, acc);
            acc = fmaf(e4.y, ov.y, acc);
            acc = fmaf(e4.z, ov.z, acc);
            acc = fmaf(e4.w, ov.w, acc);
          }
          SRED(n, qd) = acc;
        }
      }
    }
    __syncthreads();
    // PH7b: logits
    if (tl < NNODE) {
      float4 r = *(const float4*)&SRED(tl, 0);
      float tot = (r.x + r.y) + (r.z + r.w);
      float x = tanhf(tot * NORM_PROB) * 10.f;
      S.c2[tl] = (S.mask[tl] > 0.5f) ? NEG_INF : x;
    }
    __syncthreads();

    // PH8: argmax (first-index ties) + logsumexp + scalar state update (wave 0)
    if (tl < 64) {
      int lane = tl;
      float v0 = S.c2[lane];
      float v1 = (lane < NNODE - 64) ? S.c2[lane + 64] : NEG_INF;
      float bv; int bi;
      if (v1 > v0) { bv = v1; bi = lane + 64; } else { bv = v0; bi = lane; }
      #pragma unroll
      for (int o = 32; o > 0; o >>= 1) {
        float ov = __shfl_xor(bv, o, 64);
        int   oi = __shfl_xor(bi, o, 64);
        if (ov > bv || (ov == bv && oi < bi)) { bv = ov; bi = oi; }
      }
      float e0 = expf(v0 - bv);
      float e1 = (lane < NNODE - 64) ? expf(v1 - bv) : 0.f;
      float ss = e0 + e1;
      #pragma unroll
      for (int o = 32; o > 0; o >>= 1) ss += __shfl_xor(ss, o, 64);
      int c = 0;
      if (lane >= 1 && S.mask1[lane] > 0.5f) c++;
      if (lane + 64 < NNODE && S.mask1[lane + 64] > 0.5f) c++;
      #pragma unroll
      for (int o = 32; o > 0; o >>= 1) c += __shfl_xor(c, o, 64);
      if (lane == 0) {
        if (c < NNODE - 1) S.lp += -logf(ss);             // is_done gating (pre-update mask1)
        d_out[(size_t)b * NSTEP + step] = (float)bi;
        S.cap = (bi < 1) ? cap0 : (S.cap - S.dem[bi]);
        S.idx = bi;
      }
    }
    __syncthreads();

    // PH9: new input row (from LDS) + mask/mask1 update with NEW cap
    {
      int idx = S.idx;
      S.in_[j] = EL(idx, j);
      if (tl < NNODE) {
        float v1;
        if (tl == 0) v1 = (idx < 1) ? 1.f : 0.f;          // mask1[:, :nd] rule (nd=1)
        else         v1 = (tl == idx) ? 1.f : S.mask1[tl];
        S.mask1[tl] = v1;
        S.mask[tl] = (S.dem[tl] > S.cap) ? 1.f : v1;
      }
      __syncthreads();
      if (tl < 64) {
        bool ok = (tl == 0) || (S.mask[tl] > 0.5f);
        if (tl + 64 < NNODE) ok = ok && (S.mask[tl + 64] > 0.5f);
        bool alld = __all(ok);
        if (alld && tl == 0) S.mask[0] = 0.f;             // reopen depot when all done
      }
      __syncthreads();
    }
  }

  if (tl == 0) d_out[(size_t)BTOT * NSTEP + b] = S.lp;
}

extern "C" void kernel_launch(void* const* d_in, const int* in_sizes, int n_in,
                              void* d_out, int out_size, void* d_ws, size_t ws_size,
                              hipStream_t stream) {
  const float* enc   = (const float*)d_in[0];
  const float* pool  = (const float*)d_in[1];
  const float* cap   = (const float*)d_in[2];
  const float* dem   = (const float*)d_in[3];
  const float* fc_w  = (const float*)d_in[7];
  const float* fc1_w = (const float*)d_in[8];
  const float* pk_w  = (const float*)d_in[9];
  const float* mw_w  = (const float*)d_in[10];
  const float* mk_w  = (const float*)d_in[11];
  const float* mv_w  = (const float*)d_in[12];
  const float* mfc_w = (const float*)d_in[13];
  float* out = (float*)d_out;
  float* ws  = (float*)d_ws;

  prep_weights<<<321, 256, 0, stream>>>(fc_w, fc1_w, mw_w, mv_w, mfc_w, pk_w, ws);
  decoder_loop<<<BTOT, 128, 0, stream>>>(enc, pool, cap, dem, mk_w, ws, out);
}

// Round 5
// 12519.941 us; speedup vs baseline: 3.0065x; 1.4158x over previous
//
#include <hip/hip_runtime.h>

#define NNODE 101
#define DIM   128
#define NHEAD 8
#define NSTEP 150
#define BTOT  2048
#define ENCP  132          // padded enc row stride in LDS (bank-quad spread)

#define OFF_FCT  0
#define OFF_FC1T 16512
#define OFF_MWT  (OFF_FC1T + 16384)
#define OFF_MVT  (OFF_MWT + 16384)
#define OFF_F    (OFF_MVT + 16384)
#define NORM_PROB 0.08838834764831845f

// One block = one batch element, 256 threads (4 waves), enc slice resident in LDS.
// All reduction chains keep R4's exact sequential order; only thread ownership changed.
struct __align__(16) BS {
  float enc[NNODE * ENCP];   // 53328 B
  float in_[DIM];
  float pl[DIM];
  float dec[DIM];            // holds a_fc only; PH2 adds pl inline (same float value)
  float q[DIM];
  float attn[DIM];
  float op[DIM];
  float U[2112];
  float sc[1212];
  float c2[NNODE];
  float mask[NNODE];
  float mask1[NNODE];
  float dem[NNODE];
  float cap;
  float lp;
  int   idx;
};

#define EL(n,i)     S.enc[(n)*ENCP + (i)]
#define QK(h,i)     S.U[(h)*132 + (i)]
#define ZR(h,i)     S.U[(h)*132 + (i)]
#define CMP(h,n)    S.U[1056 + (h)*104 + (n)]
#define SC(n,h)     S.sc[(n)*12 + (h)]
#define SRED(n,k)   S.sc[(n)*12 + (k)]

// Transpose weights + fuse F = mfc_w^T @ pk_w (once per call)
__global__ void prep_weights(const float* __restrict__ fc_w,
                             const float* __restrict__ fc1_w,
                             const float* __restrict__ mw_w,
                             const float* __restrict__ mv_w,
                             const float* __restrict__ mfc_w,
                             const float* __restrict__ pk_w,
                             float* __restrict__ ws) {
  int x = blockIdx.x * 256 + threadIdx.x;
  if (x < 16512) { int i = x >> 7, j = x & 127; ws[OFF_FCT + x] = fc_w[j * 129 + i]; return; }
  x -= 16512;
  if (x < 16384) { int i = x >> 7, j = x & 127; ws[OFF_FC1T + x] = fc1_w[j * 128 + i]; return; }
  x -= 16384;
  if (x < 16384) { int i = x >> 7, j = x & 127; ws[OFF_MWT + x] = mw_w[j * 128 + i]; return; }
  x -= 16384;
  if (x < 16384) { int i = x >> 7, j = x & 127; ws[OFF_MVT + x] = mv_w[j * 128 + i]; return; }
  x -= 16384;
  if (x < 16384) {
    int i2 = x >> 7, i = x & 127;
    float acc = 0.f;
    for (int d = 0; d < 128; ++d)
      acc = fmaf(mfc_w[d * 128 + i2], pk_w[d * 128 + i], acc);
    ws[OFF_F + x] = acc;
  }
}

__global__ __launch_bounds__(256, 2) void decoder_loop(
    const float* __restrict__ enc, const float* __restrict__ pool,
    const float* __restrict__ capcity, const float* __restrict__ demand,
    const float* __restrict__ mk_w,
    const float* __restrict__ ws, float* __restrict__ d_out) {
  const float* fcT  = ws + OFF_FCT;
  const float* fc1T = ws + OFF_FC1T;
  const float* mwT  = ws + OFF_MWT;
  const float* mvT  = ws + OFF_MVT;
  const float* Fm   = ws + OFF_F;

  __shared__ BS S;

  const int tl   = threadIdx.x;        // 0..255
  const int j    = tl & 127;
  const int half = tl >> 7;            // wave-uniform
  const int b    = blockIdx.x;
  const size_t encB = (size_t)b * NNODE * DIM;
  const float NEG_INF = -__builtin_inff();
  const float cap0 = capcity[0];

  // ---- stage enc slice into LDS (padded rows), coalesced float4 ----
  for (int x = tl; x < NNODE * 32; x += 256) {
    int n = x >> 5, c = x & 31;
    float4 v = *(const float4*)(enc + encB + (size_t)n * DIM + c * 4);
    *(float4*)&EL(n, c * 4) = v;
  }
  __syncthreads();

  // ---- init carry ----
  if (tl < 128) {
    S.in_[tl] = EL(0, tl);                             // input0 = enc[b,0,:]
    S.pl[tl]  = pool[(size_t)b * DIM + tl];
  }
  if (tl < NNODE) {
    S.dem[tl]   = demand[(size_t)b * NNODE + tl];
    S.mask1[tl] = 0.f;
  }
  if (tl == 0) { S.cap = capcity[b]; S.lp = 0.f; S.idx = 0; }
  __syncthreads();
  // mask_update(cap, idx=0)
  {
    if (tl < NNODE) {
      float v1 = (tl == 0) ? 1.f : 0.f;
      S.mask1[tl] = v1;
      S.mask[tl] = (S.dem[tl] > S.cap) ? 1.f : v1;
    }
    __syncthreads();
    if (tl < 64) {
      bool ok = (tl == 0) || (S.mask[tl] > 0.5f);
      if (tl + 64 < NNODE) ok = ok && (S.mask[tl + 64] > 0.5f);
      bool alld = __all(ok);
      if (alld && tl == 0) S.mask[0] = 0.f;
    }
    __syncthreads();
  }

  for (int step = 0; step < NSTEP; ++step) {
    const float cap = S.cap;

    // PH1: waves 0-1: a_fc chain (fc_w); waves 2-3: a_pl chain (fc1_w).
    // Orders identical to R4; dec stores a_fc, pl stores new a_pl.
    {
      float a = 0.f;
      if (half == 0) {
        const float4* x4 = (const float4*)&S.in_[0];
        #pragma unroll 4
        for (int i4 = 0; i4 < 32; ++i4) {
          float4 xv = x4[i4];
          const float* wf = fcT + (i4 * 4) * DIM + j;
          a = fmaf(xv.x, wf[0],       a);
          a = fmaf(xv.y, wf[DIM],     a);
          a = fmaf(xv.z, wf[2 * DIM], a);
          a = fmaf(xv.w, wf[3 * DIM], a);
        }
        a = fmaf(cap, fcT[DIM * DIM + j], a);
      } else {
        const float4* p4 = (const float4*)&S.pl[0];
        #pragma unroll 4
        for (int i4 = 0; i4 < 32; ++i4) {
          float4 pv = p4[i4];
          const float* wp = fc1T + (i4 * 4) * DIM + j;
          a = fmaf(pv.x, wp[0],       a);
          a = fmaf(pv.y, wp[DIM],     a);
          a = fmaf(pv.z, wp[2 * DIM], a);
          a = fmaf(pv.w, wp[3 * DIM], a);
        }
      }
      __syncthreads();
      if (half == 0) S.dec[j] = a; else S.pl[j] = a;
    }
    __syncthreads();

    // PH2: Q = (dec+pl) @ mw_w^T — (a_fc + a_pl) recomputed inline, same float value
    if (half == 0) {
      const float4* x4 = (const float4*)&S.dec[0];
      const float4* p4 = (const float4*)&S.pl[0];
      float acc = 0.f;
      #pragma unroll 4
      for (int i4 = 0; i4 < 32; ++i4) {
        float4 xv = x4[i4], pv = p4[i4];
        const float* w = mwT + (i4 * 4) * DIM + j;
        acc = fmaf(xv.x + pv.x, w[0],       acc);
        acc = fmaf(xv.y + pv.y, w[DIM],     acc);
        acc = fmaf(xv.z + pv.z, w[2 * DIM], acc);
        acc = fmaf(xv.w + pv.w, w[3 * DIM], acc);
      }
      S.q[j] = acc;
    }
    __syncthreads();

    // PH2b: qk[h][j], 2 heads per thread (half picks head pair block)
    {
      const float4* q4 = (const float4*)&S.q[0];
      int hb = half * 4;
      #pragma unroll
      for (int hh = 0; hh < 4; ++hh) {
        int h = hb + hh;
        float4 qa = q4[h * 4 + 0], qb = q4[h * 4 + 1], qc = q4[h * 4 + 2], qd4 = q4[h * 4 + 3];
        const float* w = mk_w + (h * 16) * DIM + j;
        float acc = 0.f;
        acc = fmaf(qa.x, w[0],        acc); acc = fmaf(qa.y, w[DIM],      acc);
        acc = fmaf(qa.z, w[2 * DIM],  acc); acc = fmaf(qa.w, w[3 * DIM],  acc);
        acc = fmaf(qb.x, w[4 * DIM],  acc); acc = fmaf(qb.y, w[5 * DIM],  acc);
        acc = fmaf(qb.z, w[6 * DIM],  acc); acc = fmaf(qb.w, w[7 * DIM],  acc);
        acc = fmaf(qc.x, w[8 * DIM],  acc); acc = fmaf(qc.y, w[9 * DIM],  acc);
        acc = fmaf(qc.z, w[10 * DIM], acc); acc = fmaf(qc.w, w[11 * DIM], acc);
        acc = fmaf(qd4.x, w[12 * DIM], acc); acc = fmaf(qd4.y, w[13 * DIM], acc);
        acc = fmaf(qd4.z, w[14 * DIM], acc); acc = fmaf(qd4.w, w[15 * DIM], acc);
        QK(h, j) = acc;
      }
    }
    __syncthreads();

    // PH3: comp[h][n] = 0.25 * enc[n].qk[h] — nb now 0..31, 4 rows per thread
    {
      int h = tl & 7, nb = tl >> 3;       // nb in 0..31
      float acc[4] = {0.f, 0.f, 0.f, 0.f};
      for (int i4 = 0; i4 < 32; ++i4) {
        float4 qv = *(const float4*)&QK(h, i4 * 4);
        #pragma unroll
        for (int p = 0; p < 4; ++p) {
          int n = p * 32 + nb;
          if (n < NNODE) {
            float4 e4 = *(const float4*)&EL(n, i4 * 4);
            acc[p] = fmaf(e4.x, qv.x, acc[p]);
            acc[p] = fmaf(e4.y, qv.y, acc[p]);
            acc[p] = fmaf(e4.z, qv.z, acc[p]);
            acc[p] = fmaf(e4.w, qv.w, acc[p]);
          }
        }
      }
      #pragma unroll
      for (int p = 0; p < 4; ++p) {
        int n = p * 32 + nb;
        if (n < NNODE)
          CMP(h, n) = (S.mask[n] > 0.5f) ? NEG_INF : 0.25f * acc[p];
      }
    }
    __syncthreads();

    // PH4: softmax rows; 4 waves x 2 heads; write transposed sc[n][h]
    {
      int w = tl >> 6, lane = tl & 63;
      int hb = w * 2;
      #pragma unroll
      for (int hh = 0; hh < 2; ++hh) {
        int h = hb + hh;
        float v0 = CMP(h, lane);
        float v1 = (lane < NNODE - 64) ? CMP(h, lane + 64) : NEG_INF;
        float m = fmaxf(v0, v1);
        #pragma unroll
        for (int o = 32; o > 0; o >>= 1) m = fmaxf(m, __shfl_xor(m, o, 64));
        float e0 = expf(v0 - m);
        float e1 = (lane < NNODE - 64) ? expf(v1 - m) : 0.f;
        float ss = e0 + e1;
        #pragma unroll
        for (int o = 32; o > 0; o >>= 1) ss += __shfl_xor(ss, o, 64);
        SC(lane, h) = e0 / ss;
        if (lane < NNODE - 64) SC(lane + 64, h) = e1 / ss;
      }
    }
    __syncthreads();

    // PH5: z[h][j] = sum_n sc[n][h]*enc[n][j] — 4 heads per thread (by half)
    {
      int hb = half * 4;
      float acc[4] = {0.f, 0.f, 0.f, 0.f};
      #pragma unroll 4
      for (int n = 0; n < NNODE; ++n) {
        float4 s = *(const float4*)&SC(n, hb);
        float ev = EL(n, j);
        acc[0] = fmaf(s.x, ev, acc[0]);
        acc[1] = fmaf(s.y, ev, acc[1]);
        acc[2] = fmaf(s.z, ev, acc[2]);
        acc[3] = fmaf(s.w, ev, acc[3]);
      }
      // ZR (=QK region) last read in PH3, guarded by PH3/PH4 barriers -> safe
      #pragma unroll
      for (int hh = 0; hh < 4; ++hh) ZR(hb + hh, j) = acc[hh];
    }
    __syncthreads();

    // PH5b: attn[j] = sum_i z[h(j)][i] * mv_w[j][i]
    if (half == 0) {
      int h = j >> 4;
      float acc = 0.f;
      #pragma unroll 4
      for (int i4 = 0; i4 < 32; ++i4) {
        float4 zv = *(const float4*)&ZR(h, i4 * 4);
        const float* w = mvT + (i4 * 4) * DIM + j;
        acc = fmaf(zv.x, w[0],       acc);
        acc = fmaf(zv.y, w[DIM],     acc);
        acc = fmaf(zv.z, w[2 * DIM], acc);
        acc = fmaf(zv.w, w[3 * DIM], acc);
      }
      S.attn[j] = acc;
    }
    __syncthreads();

    // PH6: op[j] = sum_i attn[i] * F[i][j]
    if (half == 0) {
      const float4* x4 = (const float4*)&S.attn[0];
      float acc = 0.f;
      #pragma unroll 4
      for (int i4 = 0; i4 < 32; ++i4) {
        float4 xv = x4[i4];
        const float* w = Fm + (i4 * 4) * DIM + j;
        acc = fmaf(xv.x, w[0],       acc);
        acc = fmaf(xv.y, w[DIM],     acc);
        acc = fmaf(xv.z, w[2 * DIM], acc);
        acc = fmaf(xv.w, w[3 * DIM], acc);
      }
      S.op[j] = acc;
    }
    __syncthreads();

    // PH7: comp2[n] = enc[n].op — 4-way dim split, nq now 0..63, 2 rows per thread
    {
      int qd = tl & 3, nq = tl >> 2;       // nq 0..63
      #pragma unroll
      for (int p = 0; p < 2; ++p) {
        int n = p * 64 + nq;
        if (n < NNODE) {
          float acc = 0.f;
          #pragma unroll
          for (int i4 = 0; i4 < 8; ++i4) {
            float4 ov = *(const float4*)&S.op[qd * 32 + i4 * 4];
            float4 e4 = *(const float4*)&EL(n, qd * 32 + i4 * 4);
            acc = fmaf(e4.x, ov.x, acc);
            acc = fmaf(e4.y, ov.y, acc);
            acc = fmaf(e4.z, ov.z, acc);
            acc = fmaf(e4.w, ov.w, acc);
          }
          SRED(n, qd) = acc;
        }
      }
    }
    __syncthreads();
    // PH7b: logits
    if (tl < NNODE) {
      float4 r = *(const float4*)&SRED(tl, 0);
      float tot = (r.x + r.y) + (r.z + r.w);
      float x = tanhf(tot * NORM_PROB) * 10.f;
      S.c2[tl] = (S.mask[tl] > 0.5f) ? NEG_INF : x;
    }
    __syncthreads();

    // PH8: argmax (first-index ties) + logsumexp + scalar state update (wave 0)
    if (tl < 64) {
      int lane = tl;
      float v0 = S.c2[lane];
      float v1 = (lane < NNODE - 64) ? S.c2[lane + 64] : NEG_INF;
      float bv; int bi;
      if (v1 > v0) { bv = v1; bi = lane + 64; } else { bv = v0; bi = lane; }
      #pragma unroll
      for (int o = 32; o > 0; o >>= 1) {
        float ov = __shfl_xor(bv, o, 64);
        int   oi = __shfl_xor(bi, o, 64);
        if (ov > bv || (ov == bv && oi < bi)) { bv = ov; bi = oi; }
      }
      float e0 = expf(v0 - bv);
      float e1 = (lane < NNODE - 64) ? expf(v1 - bv) : 0.f;
      float ss = e0 + e1;
      #pragma unroll
      for (int o = 32; o > 0; o >>= 1) ss += __shfl_xor(ss, o, 64);
      int c = 0;
      if (lane >= 1 && S.mask1[lane] > 0.5f) c++;
      if (lane + 64 < NNODE && S.mask1[lane + 64] > 0.5f) c++;
      #pragma unroll
      for (int o = 32; o > 0; o >>= 1) c += __shfl_xor(c, o, 64);
      if (lane == 0) {
        if (c < NNODE - 1) S.lp += -logf(ss);             // is_done gating (pre-update mask1)
        d_out[(size_t)b * NSTEP + step] = (float)bi;
        S.cap = (bi < 1) ? cap0 : (S.cap - S.dem[bi]);
        S.idx = bi;
      }
    }
    __syncthreads();

    // PH9: new input row (from LDS) + mask/mask1 update with NEW cap
    {
      int idx = S.idx;
      if (tl < 128) S.in_[tl] = EL(idx, tl);
      if (tl < NNODE) {
        float v1;
        if (tl == 0) v1 = (idx < 1) ? 1.f : 0.f;          // mask1[:, :nd] rule (nd=1)
        else         v1 = (tl == idx) ? 1.f : S.mask1[tl];
        S.mask1[tl] = v1;
        S.mask[tl] = (S.dem[tl] > S.cap) ? 1.f : v1;
      }
      __syncthreads();
      if (tl < 64) {
        bool ok = (tl == 0) || (S.mask[tl] > 0.5f);
        if (tl + 64 < NNODE) ok = ok && (S.mask[tl + 64] > 0.5f);
        bool alld = __all(ok);
        if (alld && tl == 0) S.mask[0] = 0.f;             // reopen depot when all done
      }
      __syncthreads();
    }
  }

  if (tl == 0) d_out[(size_t)BTOT * NSTEP + b] = S.lp;
}

extern "C" void kernel_launch(void* const* d_in, const int* in_sizes, int n_in,
                              void* d_out, int out_size, void* d_ws, size_t ws_size,
                              hipStream_t stream) {
  const float* enc   = (const float*)d_in[0];
  const float* pool  = (const float*)d_in[1];
  const float* cap   = (const float*)d_in[2];
  const float* dem   = (const float*)d_in[3];
  const float* fc_w  = (const float*)d_in[7];
  const float* fc1_w = (const float*)d_in[8];
  const float* pk_w  = (const float*)d_in[9];
  const float* mw_w  = (const float*)d_in[10];
  const float* mk_w  = (const float*)d_in[11];
  const float* mv_w  = (const float*)d_in[12];
  const float* mfc_w = (const float*)d_in[13];
  float* out = (float*)d_out;
  float* ws  = (float*)d_ws;

  prep_weights<<<321, 256, 0, stream>>>(fc_w, fc1_w, mw_w, mv_w, mfc_w, pk_w, ws);
  decoder_loop<<<BTOT, 256, 0, stream>>>(enc, pool, cap, dem, mk_w, ws, out);
}